// Round 5
// baseline (43.451 us; speedup 1.0000x reference)
//
#include <hip/hip_runtime.h>
#include <math.h>

#define HD 512
#define WD 512
#define NP 255          // patch grid = 255 x 255
#define LP (NP * NP)    // 65025 patches
#define LK (LP / 9)     // 7225 patches per kk-group
#define BATCH 32
#define RB 128          // r's per chunk
#define G  3            // chunks per block
#define QB 19           // blocks per (b,di): QB*G = 57 = ceil(LK/RB) exactly
#define NTHR 384        // 3 dj-groups x 128 r
#define MAXROWS 6       // max pi2 span for 1152 consecutive ll
#define PAR 256         // floats per parity row (= NP+1; wrap bump relies on this)

// Semantics (reference's flat reshape (b,9,L)->(b,L,9)):
//   l = kk*7225 + r ; (di,dj) = (kk/3, kk%3) fixed within a 9-group
//   k in 0..8: ll = 9r+k -> pixel (2*(ll/255)+di, 2*(ll%255)+dj)
//   argmin/argmax |a-c| (first-occurrence), s = c[argmin]+c[argmax]
//   broadcast to 2x2 (3x3 at edges) block of patch (l/255, l%255); row/col 511 = 0.
//
// Block = (b, di, 3 consecutive 128-r chunks). Pipeline: chunk c+1 global->reg
// loads issue before chunk c's compute (latency hidden under ds_reads+VALU+stores);
// reg->LDS as contiguous float4 parity writes (conflict-minimal); compute reads
// lane-stride 9 floats (gcd(9,32)=1, conflict-free).
__global__ __launch_bounds__(NTHR) void dc_pool_kernel(
    const float* __restrict__ anchor,
    const float* __restrict__ pos,
    const float* __restrict__ neg,
    float* __restrict__ out0,
    float* __restrict__ out1)
{
    __shared__ float lAe[MAXROWS * PAR], lAo[MAXROWS * PAR];
    __shared__ float lPe[MAXROWS * PAR], lPo[MAXROWS * PAR];
    __shared__ float lNe[MAXROWS * PAR], lNo[MAXROWS * PAR];

    int bid = blockIdx.x;
    int q   = bid % QB;
    int t2  = bid / QB;
    int di  = t2 % 3;
    int b   = t2 / 3;
    int rb0 = q * G;

    const size_t plane = (size_t)HD * WD;
    const float* A = anchor + (size_t)b * plane;
    const float* P = pos    + (size_t)b * plane;
    const float* N = neg    + (size_t)b * plane;
    float* O0 = out0 + (size_t)b * plane;
    float* O1 = out1 + (size_t)b * plane;

    int tid = threadIdx.x;
    int dj  = tid / RB;            // 0..2
    int idx = tid - dj * RB;       // 0..127
    const int slot = tid;
    const int srow = slot >> 6;            // staging row 0..5
    const int sc8  = (slot & 63) << 3;     // staging col (8 floats per thread)
    const int s_lo = srow * PAR + (sc8 >> 1);

    // prefetch registers (one chunk in flight)
    bool   s_act = false;
    float4 sA0, sA1, sP0, sP1, sN0, sN1;

    auto load_chunk = [&](int rb) {
        int r0     = rb * RB;
        int rcount = min(RB, LK - r0);
        int llb    = 9 * r0;
        int pi2min = llb / NP;
        int rows   = (llb + 9 * rcount - 1) / NP - pi2min + 1;   // <= 6
        s_act = slot < rows * 64;
        if (s_act) {
            size_t go = (size_t)(2 * (pi2min + srow) + di) * WD + sc8;
            sA0 = *reinterpret_cast<const float4*>(A + go);
            sA1 = *reinterpret_cast<const float4*>(A + go + 4);
            sP0 = *reinterpret_cast<const float4*>(P + go);
            sP1 = *reinterpret_cast<const float4*>(P + go + 4);
            sN0 = *reinterpret_cast<const float4*>(N + go);
            sN1 = *reinterpret_cast<const float4*>(N + go + 4);
        }
    };

    auto write_chunk = [&]() {
        if (s_act) {
            *reinterpret_cast<float4*>(&lAe[s_lo]) = make_float4(sA0.x, sA0.z, sA1.x, sA1.z);
            *reinterpret_cast<float4*>(&lAo[s_lo]) = make_float4(sA0.y, sA0.w, sA1.y, sA1.w);
            *reinterpret_cast<float4*>(&lPe[s_lo]) = make_float4(sP0.x, sP0.z, sP1.x, sP1.z);
            *reinterpret_cast<float4*>(&lPo[s_lo]) = make_float4(sP0.y, sP0.w, sP1.y, sP1.w);
            *reinterpret_cast<float4*>(&lNe[s_lo]) = make_float4(sN0.x, sN0.z, sN1.x, sN1.z);
            *reinterpret_cast<float4*>(&lNo[s_lo]) = make_float4(sN0.y, sN0.w, sN1.y, sN1.w);
        }
    };

    auto compute_chunk = [&](int rb) {
        int r0     = rb * RB;
        int rcount = min(RB, LK - r0);
        if (idx >= rcount) return;         // guard only; barriers are outside
        int pi2min = (9 * r0) / NP;

        int r    = r0 + idx;
        int ll0  = 9 * r;
        int pi2  = ll0 / NP;
        int pj2  = ll0 - pi2 * NP;
        const float* sA = (dj == 1) ? lAo : lAe;
        const float* sP = (dj == 1) ? lPo : lPe;
        const float* sN = (dj == 1) ? lNo : lNe;
        int base  = (pi2 - pi2min) * PAR + pj2 + ((dj == 2) ? 1 : 0);
        int wrapk = NP - pj2;              // k >= wrapk -> next image row (+1; PAR=NP+1)

        float minvP = 0.f, maxvP = 0.f, mindP = INFINITY, maxdP = -INFINITY;
        float minvN = 0.f, maxvN = 0.f, mindN = INFINITY, maxdN = -INFINITY;
        #pragma unroll
        for (int k = 0; k < 9; ++k) {
            int lo = base + k + ((k >= wrapk) ? 1 : 0);
            float a = sA[lo];
            float p = sP[lo];
            float n = sN[lo];
            float dp = fabsf(a - p);
            float dn = fabsf(a - n);
            if (dp < mindP) { mindP = dp; minvP = p; }   // first-occurrence argmin
            if (dp > maxdP) { maxdP = dp; maxvP = p; }   // first-occurrence argmax
            if (dn < mindN) { mindN = dn; minvN = n; }
            if (dn > maxdN) { maxdN = dn; maxvN = n; }
        }
        float s0 = minvP + maxvP;
        float s1 = minvN + maxvN;

        int kk  = 3 * di + dj;
        int l   = kk * LK + r;
        int piy = l / NP;
        int pjx = l - piy * NP;
        int y0  = 2 * piy;
        int x0  = 2 * pjx;
        bool right  = (pjx == NP - 1);
        bool bottom = (piy == NP - 1);
        int ny = bottom ? 3 : 2;

        for (int yy = 0; yy < ny; ++yy) {
            float* p0 = O0 + (size_t)(y0 + yy) * WD + x0;
            float* p1 = O1 + (size_t)(y0 + yy) * WD + x0;
            if (right) {    // cols 508,509,510 = s ; col 511 = 0
                *reinterpret_cast<float4*>(p0) = make_float4(s0, s0, s0, 0.f);
                *reinterpret_cast<float4*>(p1) = make_float4(s1, s1, s1, 0.f);
            } else {
                *reinterpret_cast<float2*>(p0) = make_float2(s0, s0);
                *reinterpret_cast<float2*>(p1) = make_float2(s1, s1);
            }
        }
        if (bottom) {       // row 511 = 0
            float* p0 = O0 + (size_t)(HD - 1) * WD + x0;
            float* p1 = O1 + (size_t)(HD - 1) * WD + x0;
            if (right) {
                *reinterpret_cast<float4*>(p0) = make_float4(0.f, 0.f, 0.f, 0.f);
                *reinterpret_cast<float4*>(p1) = make_float4(0.f, 0.f, 0.f, 0.f);
            } else {
                *reinterpret_cast<float2*>(p0) = make_float2(0.f, 0.f);
                *reinterpret_cast<float2*>(p1) = make_float2(0.f, 0.f);
            }
        }
    };

    // ---- pipelined chunk loop: load(c+1) issues before compute(c) ----
    load_chunk(rb0);
    write_chunk();
    __syncthreads();
    #pragma unroll
    for (int c = 0; c < G; ++c) {
        if (c + 1 < G) load_chunk(rb0 + c + 1);   // in flight during compute
        compute_chunk(rb0 + c);
        if (c + 1 < G) {
            __syncthreads();                       // all reads of chunk c done
            write_chunk();
            __syncthreads();                       // chunk c+1 visible
        }
    }
}

extern "C" void kernel_launch(void* const* d_in, const int* in_sizes, int n_in,
                              void* d_out, int out_size, void* d_ws, size_t ws_size,
                              hipStream_t stream) {
    const float* anchor = (const float*)d_in[0];
    const float* pos    = (const float*)d_in[1];
    const float* neg    = (const float*)d_in[2];
    float* out0 = (float*)d_out;
    float* out1 = out0 + (size_t)BATCH * HD * WD;

    int grid = BATCH * 3 * QB;   // 32 * 3 * 19 = 1824 blocks
    dc_pool_kernel<<<grid, NTHR, 0, stream>>>(anchor, pos, neg, out0, out1);
}